// Round 1
// 894.068 us; speedup vs baseline: 1.0714x; 1.0714x over previous
//
#include <hip/hip_runtime.h>
#include <hip/hip_bf16.h>
#include <stdint.h>

typedef __bf16 bf16;
typedef __bf16 bf16x8 __attribute__((ext_vector_type(8)));
typedef __bf16 bf16x4v __attribute__((ext_vector_type(4)));
typedef float f32x4 __attribute__((ext_vector_type(4)));

#define AS1 __attribute__((address_space(1)))
#define AS3 __attribute__((address_space(3)))

__device__ __forceinline__ void g2lds16(const bf16* g, bf16* l) {
  // global -> LDS async copy, 16 B/lane. LDS dest must be wave-uniform base + lane*16.
  __builtin_amdgcn_global_load_lds((AS1 void*)(uintptr_t)g, (AS3 void*)l, 16, 0, 0);
}

// ---------------- prep: fold s (and 1/sqrt(C) into layer 3) into W, cast bf16 ----------------
// Also builds W24 = concat(W2', W4') rows for the merged fo0+fd0 GEMM.
__global__ void prep_weights_k(const float* __restrict__ W, const float* __restrict__ s,
                               const float* __restrict__ b, bf16* __restrict__ Wb,
                               float* __restrict__ bb, bf16* __restrict__ W24,
                               float* __restrict__ b24) {
  int idx = blockIdx.x * 256 + threadIdx.x;     // 7*512*512 threads
  int c = idx & 511;
  int o = (idx >> 9) & 511;
  int l = idx >> 18;
  const float r = 0.04419417382415922f;         // 1/sqrt(512), folded into f_object layer 2 (idx 3)
  float f = (l == 3) ? r : 1.0f;
  float wv = W[idx] * s[(l << 9) + o] * f;
  float bv = b[(l << 9) + o] * f;
  Wb[idx] = (bf16)wv;
  if (c == 0) bb[(l << 9) + o] = bv;
  if (l == 2) { W24[(size_t)o * 512 + c] = (bf16)wv;         if (c == 0) b24[o] = bv; }
  if (l == 4) { W24[(size_t)(512 + o) * 512 + c] = (bf16)wv; if (c == 0) b24[512 + o] = bv; }
}

// ---------------- transpose + cast: in [z][R][S] f32 -> out [z][S][R] bf16 ----------------
__global__ void transpose_cast_k(const float* __restrict__ in, bf16* __restrict__ out,
                                 int R, int S) {
  __shared__ float tile[64][65];
  int s0 = blockIdx.x * 64, r0 = blockIdx.y * 64;
  size_t zo = (size_t)blockIdx.z * R * S;
  int t = threadIdx.x;          // 256
  int rr = t >> 4, cc = t & 15;
#pragma unroll
  for (int i = 0; i < 4; i++) {
    float4 v = *(const float4*)&in[zo + (size_t)(r0 + rr + 16 * i) * S + s0 + cc * 4];
    tile[rr + 16 * i][cc * 4 + 0] = v.x;
    tile[rr + 16 * i][cc * 4 + 1] = v.y;
    tile[rr + 16 * i][cc * 4 + 2] = v.z;
    tile[rr + 16 * i][cc * 4 + 3] = v.w;
  }
  __syncthreads();
#pragma unroll
  for (int i = 0; i < 4; i++) {
    int sR = rr + 16 * i;       // row of out (S dim)
    bf16x4v o;
    o.x = (bf16)tile[cc * 4 + 0][sR];
    o.y = (bf16)tile[cc * 4 + 1][sR];
    o.z = (bf16)tile[cc * 4 + 2][sR];
    o.w = (bf16)tile[cc * 4 + 3][sR];
    *(bf16x4v*)&out[zo + (size_t)(s0 + sR) * R + r0 + cc * 4] = o;
  }
}

// ---------------- 256x256 8-phase NT GEMM (T2 swizzle + T3/T4 counted vmcnt + T5 setprio) ----
// A: [z][M][.] row-stride lda (K contig), B: [z][N][.] row-stride ldb (K contig),
// OUT: [z][M][N] (N contig). OUT = act(A.B^T + bias).
// Requires: M%256==0, N%256==0, Kd%128==0 (nk even, >=2).
// Geometry: BM=BN=256, BK=64, 8 waves (2M x 4N), per-wave C = 128x64, acc[8][4] f32x4.
// LDS: sm[buf][A/B][256][64] bf16 = 128 KiB, double-buffered K-tiles (even->buf0, odd->buf1).
// Swizzle: physical 16B chunk = logical chunk ^ (row&7); global source pre-swizzled so the
// linear global_load_lds dest + swizzled ds_read agree (both-sides-or-neither rule).
// Stage schedule (half-tile per phase; clobber >= 1 full phase after region's last read):
//   ph1 Ah0(T+1) | ph2 Ah1(T+1) | ph3 Bh0(T+2) | ph4 Bh1(T+2)+vmcnt(4)
//   ph5 Ah0(T+2) | ph6 Ah1(T+2) | ph7 Bh0(T+3) | ph8 Bh1(T+3)+vmcnt(4)
// vmcnt(4): 12 loads in flight at each wait; retire oldest 8 = next tile's 4 halves.

#define MFMA16(AF, BF, IO, JO)                                                \
  __builtin_amdgcn_s_setprio(1);                                              \
  _Pragma("unroll") for (int kx = 0; kx < 2; kx++)                            \
  _Pragma("unroll") for (int i = 0; i < 4; i++)                               \
  _Pragma("unroll") for (int j = 0; j < 2; j++)                               \
      acc[(IO) + i][(JO) + j] = __builtin_amdgcn_mfma_f32_16x16x32_bf16(      \
          AF[i][kx], BF[j][kx], acc[(IO) + i][(JO) + j], 0, 0, 0);            \
  __builtin_amdgcn_s_setprio(0);

#define RD_A(DST, BUF, ROFF)                                                  \
  _Pragma("unroll") for (int i = 0; i < 4; i++)                               \
  _Pragma("unroll") for (int kx = 0; kx < 2; kx++) {                          \
    const int ar = wm * 128 + (ROFF) + i * 16 + fr;                           \
    DST[i][kx] = *(const bf16x8*)&sm[BUF][0][ar]                              \
        [(((kx << 2) + fq8) ^ (ar & 7)) << 3];                                \
  }

#define RD_B(DST, BUF, COFF)                                                  \
  _Pragma("unroll") for (int j = 0; j < 2; j++)                               \
  _Pragma("unroll") for (int kx = 0; kx < 2; kx++) {                          \
    const int br = wn * 64 + (COFF) + j * 16 + fr;                            \
    DST[j][kx] = *(const bf16x8*)&sm[BUF][1][br]                              \
        [(((kx << 2) + fq8) ^ (br & 7)) << 3];                                \
  }

#define PH_SYNC_PRE  __builtin_amdgcn_s_barrier(); __builtin_amdgcn_sched_barrier(0);
#define PH_SYNC_POST __builtin_amdgcn_sched_barrier(0); __builtin_amdgcn_s_barrier();

template <bool RELU, bool OUTF32, int BIASMODE>
__global__ __launch_bounds__(512, 2) void gemm_nt(
    const bf16* __restrict__ A, long sAb, int lda,
    const bf16* __restrict__ B, long sBb, int ldb,
    void* __restrict__ OUT, long sOb,
    const float* __restrict__ bias,
    int M, int N, int Kd) {
  __shared__ bf16 sm[2][2][256][64];   // [buf][0=A,1=B][row][64k] = 128 KiB
  const int t = threadIdx.x;
  const int lane = t & 63;
  const int w = t >> 6;            // 0..7
  const int wm = w >> 2;           // 0..1
  const int wn = w & 3;            // 0..3
  const int n0 = blockIdx.x * 256;
  const int m0 = blockIdx.y * 256;
  const bf16* __restrict__ Ab = A + (size_t)blockIdx.z * sAb;
  const bf16* __restrict__ Bb = B + (size_t)blockIdx.z * sBb;
  const int nk = Kd >> 6;

  // staging: thread t handles 2x16B per half-tile; linear LDS dest = base + t*16
  const int prow = t >> 3;          // 0..63 (call 0), +64 (call 1)
  const int pchunk = t & 7;
  const int lch = pchunk ^ (prow & 7);   // (prow+64)&7 == prow&7

  const int fr = lane & 15;
  const int fq8 = lane >> 4;        // 0..3

  auto stage = [&](int ab, int h, int kt) {
    const int ktc = (kt < nk) ? kt : 0;   // tail: harmless garbage into consumed slots
    const bf16* __restrict__ src = ab ? Bb : Ab;
    const int ld = ab ? ldb : lda;
    const int r0 = (ab ? n0 : m0) + h * 128;
    const int buf = kt & 1;
#pragma unroll
    for (int j = 0; j < 2; j++) {
      const int pr = j * 64 + prow;
      g2lds16(src + (size_t)(r0 + pr) * ld + (ktc << 6) + (lch << 3),
              &sm[buf][ab][h * 128 + pr][pchunk << 3]);
    }
  };

  f32x4 acc[8][4] = {};
  bf16x8 a0[4][2], a1[4][2], b0[2][2], b1[2][2];

  // prologue: tile0 fully + B-halves of tile1; retire tile0 (oldest 8 of 12)
  stage(0, 0, 0); stage(0, 1, 0); stage(1, 0, 0); stage(1, 1, 0);
  stage(1, 0, 1); stage(1, 1, 1);
  asm volatile("s_waitcnt vmcnt(4)" ::: "memory");
  __builtin_amdgcn_s_barrier();
  __builtin_amdgcn_sched_barrier(0);

  for (int T = 0; T < nk; T += 2) {
    // ---- ph1: quadrant (r0,c0) of tile T (buf0)
    RD_A(a0, 0, 0)
    RD_B(b0, 0, 0)
    stage(0, 0, T + 1);
    PH_SYNC_PRE
    MFMA16(a0, b0, 0, 0)
    PH_SYNC_POST
    // ---- ph2: (r0,c1)
    RD_B(b1, 0, 32)
    stage(0, 1, T + 1);
    PH_SYNC_PRE
    MFMA16(a0, b1, 0, 2)
    PH_SYNC_POST
    // ---- ph3: (r1,c0)
    RD_A(a1, 0, 64)
    stage(1, 0, T + 2);
    PH_SYNC_PRE
    MFMA16(a1, b0, 4, 0)
    PH_SYNC_POST
    // ---- ph4: (r1,c1); ensure tile T+1 landed before ph5 reads
    stage(1, 1, T + 2);
    PH_SYNC_PRE
    MFMA16(a1, b1, 4, 2)
    asm volatile("s_waitcnt vmcnt(4)" ::: "memory");
    PH_SYNC_POST
    // ---- ph5: quadrant (r0,c0) of tile T+1 (buf1)
    RD_A(a0, 1, 0)
    RD_B(b0, 1, 0)
    stage(0, 0, T + 2);
    PH_SYNC_PRE
    MFMA16(a0, b0, 0, 0)
    PH_SYNC_POST
    // ---- ph6: (r0,c1)
    RD_B(b1, 1, 32)
    stage(0, 1, T + 2);
    PH_SYNC_PRE
    MFMA16(a0, b1, 0, 2)
    PH_SYNC_POST
    // ---- ph7: (r1,c0)
    RD_A(a1, 1, 64)
    stage(1, 0, T + 3);
    PH_SYNC_PRE
    MFMA16(a1, b0, 4, 0)
    PH_SYNC_POST
    // ---- ph8: (r1,c1); ensure tile T+2 landed before next-iter ph1 reads
    stage(1, 1, T + 3);
    PH_SYNC_PRE
    MFMA16(a1, b1, 4, 2)
    asm volatile("s_waitcnt vmcnt(4)" ::: "memory");
    PH_SYNC_POST
  }

  // drain in-flight (possibly clamped) stages before LDS goes away / epilogue
  asm volatile("s_waitcnt vmcnt(0)" ::: "memory");

  // epilogue: C frag (row = fq8*4+reg, col = fr); acc[m][nn] -> (m*16, nn*16)
  const int rb = m0 + wm * 128 + (fq8 << 2);
  const int cb = n0 + wn * 64 + fr;
#pragma unroll
  for (int i = 0; i < 8; i++) {
#pragma unroll
    for (int r = 0; r < 4; r++) {
      const int orow = rb + i * 16 + r;
#pragma unroll
      for (int j = 0; j < 4; j++) {
        const int oc = cb + j * 16;
        float vv = acc[i][j][r];
        if (BIASMODE == 1) vv += bias[oc];
        else if (BIASMODE == 2) vv += bias[orow];
        if (RELU) vv = fmaxf(vv, 0.0f);
        if (OUTF32)
          ((float*)OUT)[(size_t)blockIdx.z * sOb + (size_t)orow * N + oc] = vv;
        else
          ((bf16*)OUT)[(size_t)blockIdx.z * sOb + (size_t)orow * N + oc] = (bf16)vv;
      }
    }
  }
}

// ---------------- sim + softmax fused: P = softmax_rows(Q.Key^T) ----------------
__global__ __launch_bounds__(256, 2) void sim_softmax_k(
    const bf16* __restrict__ Q, const bf16* __restrict__ Key, bf16* __restrict__ P) {
  __shared__ bf16 sQ[128][64];   // 16 KB
  __shared__ bf16 sK[256][64];   // 32 KB
  const int t = threadIdx.x;
  const int lane = t & 63;
  const int w = t >> 6;
  const int m0 = blockIdx.x * 128;
  const bf16* Qz = Q + (size_t)blockIdx.y * 16384 * 512;
  const bf16* Kz = Key + (size_t)blockIdx.y * 256 * 512;
  bf16* Pz = P + (size_t)blockIdx.y * 16384 * 256;

  const int fr = lane & 15;
  const int quad = lane >> 4;
  const int fq = quad << 3;
  const int wm = w << 5;            // wave's 32 q-rows
  const int srow = t >> 3;
  const int scol = (t & 7) << 3;

  f32x4 acc[2][16] = {};

  for (int k0 = 0; k0 < 512; k0 += 64) {
#pragma unroll
    for (int i = 0; i < 4; i++)
      g2lds16(Qz + (size_t)(m0 + i * 32 + srow) * 512 + k0 + scol, &sQ[i * 32 + srow][scol]);
#pragma unroll
    for (int i = 0; i < 8; i++)
      g2lds16(Kz + (size_t)(i * 32 + srow) * 512 + k0 + scol, &sK[i * 32 + srow][scol]);
    __syncthreads();
#pragma unroll
    for (int kk = 0; kk < 64; kk += 32) {
      bf16x8 aq0 = *(const bf16x8*)&sQ[wm + fr][kk + fq];
      bf16x8 aq1 = *(const bf16x8*)&sQ[wm + 16 + fr][kk + fq];
#pragma unroll
      for (int j = 0; j < 16; j++) {
        bf16x8 bk = *(const bf16x8*)&sK[j * 16 + fr][kk + fq];
        acc[0][j] = __builtin_amdgcn_mfma_f32_16x16x32_bf16(aq0, bk, acc[0][j], 0, 0, 0);
        acc[1][j] = __builtin_amdgcn_mfma_f32_16x16x32_bf16(aq1, bk, acc[1][j], 0, 0, 0);
      }
    }
    __syncthreads();
  }

#pragma unroll
  for (int i = 0; i < 2; i++) {
#pragma unroll
    for (int r = 0; r < 4; r++) {
      float m = acc[i][0][r];
#pragma unroll
      for (int j = 1; j < 16; j++) m = fmaxf(m, acc[i][j][r]);
#pragma unroll
      for (int o = 1; o < 16; o <<= 1) m = fmaxf(m, __shfl_xor(m, o));
      float sum = 0.0f;
#pragma unroll
      for (int j = 0; j < 16; j++) {
        float e = __expf(acc[i][j][r] - m);
        acc[i][j][r] = e;
        sum += e;
      }
#pragma unroll
      for (int o = 1; o < 16; o <<= 1) sum += __shfl_xor(sum, o);
      float inv = 1.0f / sum;
      const size_t rowoff = (size_t)(m0 + wm + i * 16 + (quad << 2) + r) * 256;
#pragma unroll
      for (int j = 0; j < 16; j++)
        Pz[rowoff + j * 16 + fr] = (bf16)(acc[i][j][r] * inv);
    }
  }
}

extern "C" void kernel_launch(void* const* d_in, const int* in_sizes, int n_in,
                              void* d_out, int out_size, void* d_ws, size_t ws_size,
                              hipStream_t stream) {
  const float* x = (const float*)d_in[0];      // [8, 512, 128, 128]
  const float* proxy = (const float*)d_in[1];  // [8, 512, 256]
  const float* W = (const float*)d_in[2];      // [7, 512, 512]
  const float* s = (const float*)d_in[3];      // [7, 512]
  const float* b = (const float*)d_in[4];      // [7, 512]
  float* out = (float*)d_out;                  // [8, 512, 16384] fp32

  const int C = 512, K = 256, NB = 8, HW = 16384;
  const size_t MiB = 1024 * 1024;
  char* ws = (char*)d_ws;
  if (ws_size < 272 * MiB) return;

  bf16* Wb   = (bf16*)(ws + 0);            // 3.5 MiB
  float* bb  = (float*)(ws + 3670016);
  bf16* W24  = (bf16*)(ws + 4 * MiB);      // [1024][512] = 1 MiB
  float* b24 = (float*)(ws + 5 * MiB);
  bf16* pT   = (bf16*)(ws + 6 * MiB);      // [8][256][512]
  bf16* kt   = (bf16*)(ws + 8 * MiB);      // [8][256][1024]: cols 0-511 k1, 512-1023 t2
  bf16* key  = (bf16*)(ws + 12 * MiB);     // [8][256][512] (1/sqrt(C) folded)
  bf16* v    = (bf16*)(ws + 14 * MiB);     // [8][512][256] value^T
  bf16* bufA = (bf16*)(ws + 16 * MiB);     // 128 MiB: xb -> q -> ctx
  bf16* bufB = (bf16*)(ws + 144 * MiB);    // 128 MiB: t0 -> P

  bf16* xb  = bufA;
  bf16* t0  = bufB;
  bf16* q   = bufA;   // overwrites xb (dead after fp0)
  bf16* P   = bufB;   // overwrites t0 (dead after fp1)
  bf16* ctx = bufA;   // overwrites q  (dead after sim)

  const long KC = (long)K * C;       // 131072
  const long KT = (long)K * 1024;    // 262144
  const long HWC = (long)HW * C;     // 8388608
  const long HWK = (long)HW * K;     // 4194304

  // 1. fold scales into weights (+ build W24 concat)
  prep_weights_k<<<7 * 512 * 512 / 256, 256, 0, stream>>>(W, s, b, Wb, bb, W24, b24);
  // 2. transpose+cast proxy [z,C,K] -> pT [z,K,C]
  transpose_cast_k<<<dim3(K / 64, C / 64, NB), 256, 0, stream>>>(proxy, pT, C, K);
  // 3. transpose+cast x [z,C,HW] -> xb [z,HW,C]
  transpose_cast_k<<<dim3(HW / 64, C / 64, NB), 256, 0, stream>>>(x, xb, C, HW);
  // 4. merged fo0+fd0: kt = relu(pT.W24^T + b24), N=1024
  gemm_nt<true, false, 1><<<dim3(1024 / 256, K / 256, NB), 512, 0, stream>>>(
      pT, KC, C, W24, 0, C, kt, KT, b24, K, 1024, C);
  // 5. fo1: key = relu(k1.W3'^T + b3')
  gemm_nt<true, false, 1><<<dim3(C / 256, K / 256, NB), 512, 0, stream>>>(
      kt, KT, 1024, Wb + 3 * 262144, 0, C, key, KC, bb + 3 * 512, K, C, C);
  // 6. fd1 (swapped): v[c][k] = relu(W5'.t2^T + b5)
  gemm_nt<true, false, 2><<<dim3(K / 256, C / 256, NB), 512, 0, stream>>>(
      Wb + 5 * 262144, 0, C, kt + 512, KT, 1024, v, KC, bb + 5 * 512, C, K, C);
  // 7. fp0: t0 = relu(xb.W0^T + b0)
  gemm_nt<true, false, 1><<<dim3(C / 256, HW / 256, NB), 512, 0, stream>>>(
      xb, HWC, C, Wb, 0, C, t0, HWC, bb, HW, C, C);
  // 8. fp1: q = relu(t0.W1^T + b1)
  gemm_nt<true, false, 1><<<dim3(C / 256, HW / 256, NB), 512, 0, stream>>>(
      t0, HWC, C, Wb + 1 * 262144, 0, C, q, HWC, bb + 512, HW, C, C);
  // 9. sim + softmax fused: P = softmax(q.key^T)
  sim_softmax_k<<<dim3(HW / 128, NB), 256, 0, stream>>>(q, key, P);
  // 10. ctx = P.v^T  [z][HW][512]  (K=256)
  gemm_nt<false, false, 0><<<dim3(C / 256, HW / 256, NB), 512, 0, stream>>>(
      P, HWK, K, v, KC, K, ctx, HWC, nullptr, HW, C, K);
  // 11. fup (swapped): out[c][hw] = relu(W6'.ctx^T + b6), fp32
  gemm_nt<true, true, 2><<<dim3(HW / 256, C / 256, NB), 512, 0, stream>>>(
      Wb + 6 * 262144, 0, C, ctx, HWC, C, out, HWC, bb + 6 * 512, C, HW, C);
}

// Round 3
// 873.287 us; speedup vs baseline: 1.0969x; 1.0238x over previous
//
#include <hip/hip_runtime.h>
#include <hip/hip_bf16.h>
#include <stdint.h>

typedef __bf16 bf16;
typedef __bf16 bf16x8 __attribute__((ext_vector_type(8)));
typedef float f32x4 __attribute__((ext_vector_type(4)));

#define AS1 __attribute__((address_space(1)))
#define AS3 __attribute__((address_space(3)))

__device__ __forceinline__ void g2lds16(const bf16* g, bf16* l) {
  // global -> LDS async copy, 16 B/lane. LDS dest must be wave-uniform base + lane*16.
  __builtin_amdgcn_global_load_lds((AS1 void*)(uintptr_t)g, (AS3 void*)l, 16, 0, 0);
}

// ---------------- prep: fold s (and 1/sqrt(C) into layer 3) into W, cast bf16 ----------------
__global__ void prep_weights_k(const float* __restrict__ W, const float* __restrict__ s,
                               const float* __restrict__ b, bf16* __restrict__ Wb,
                               float* __restrict__ bb, bf16* __restrict__ W24,
                               float* __restrict__ b24) {
  int idx = blockIdx.x * 256 + threadIdx.x;     // 7*512*512 threads
  int c = idx & 511;
  int o = (idx >> 9) & 511;
  int l = idx >> 18;
  const float r = 0.04419417382415922f;         // 1/sqrt(512), folded into f_object layer 2 (idx 3)
  float f = (l == 3) ? r : 1.0f;
  float wv = W[idx] * s[(l << 9) + o] * f;
  float bv = b[(l << 9) + o] * f;
  Wb[idx] = (bf16)wv;
  if (c == 0) bb[(l << 9) + o] = bv;
  if (l == 2) { W24[(size_t)o * 512 + c] = (bf16)wv;         if (c == 0) b24[o] = bv; }
  if (l == 4) { W24[(size_t)(512 + o) * 512 + c] = (bf16)wv; if (c == 0) b24[512 + o] = bv; }
}

// ---------------- transpose + cast: in [z][R][S] f32 -> out [z][S][R] bf16 ----------------
// 64x64 tile, float4 loads, bf16x8 (16 B) stores. LDS column reads are 2-way aliased (free).
__global__ void transpose_cast_k(const float* __restrict__ in, bf16* __restrict__ out,
                                 int R, int S) {
  __shared__ float tile[64][65];
  int s0 = blockIdx.x * 64, r0 = blockIdx.y * 64;
  size_t zo = (size_t)blockIdx.z * R * S;
  int t = threadIdx.x;          // 256
  int rr = t >> 4, cc = t & 15;
#pragma unroll
  for (int i = 0; i < 4; i++) {
    float4 v = *(const float4*)&in[zo + (size_t)(r0 + rr + 16 * i) * S + s0 + cc * 4];
    tile[rr + 16 * i][cc * 4 + 0] = v.x;
    tile[rr + 16 * i][cc * 4 + 1] = v.y;
    tile[rr + 16 * i][cc * 4 + 2] = v.z;
    tile[rr + 16 * i][cc * 4 + 3] = v.w;
  }
  __syncthreads();
  // thread -> out row s0+sr, cols r0 + rg*16 .. +15 (two 16 B stores)
  const int sr = t >> 2, rg = t & 3;
  bf16x8 o0, o1;
#pragma unroll
  for (int e = 0; e < 8; e++) o0[e] = (bf16)tile[rg * 16 + e][sr];
#pragma unroll
  for (int e = 0; e < 8; e++) o1[e] = (bf16)tile[rg * 16 + 8 + e][sr];
  *(bf16x8*)&out[zo + (size_t)(s0 + sr) * R + r0 + rg * 16] = o0;
  *(bf16x8*)&out[zo + (size_t)(s0 + sr) * R + r0 + rg * 16 + 8] = o1;
}

// ---------------- 256x256 8-phase NT GEMM (T2 swizzle + T3/T4 counted vmcnt + T5 setprio) ----
// A: [z][M][.] row-stride lda (K contig), B: [z][N][.] row-stride ldb (K contig),
// OUT: [z][M][N] (N contig). OUT = act(A.B^T + bias). M%256==0, N%256==0, Kd%128==0.

#define MFMA16(AF, BF, IO, JO)                                                \
  __builtin_amdgcn_s_setprio(1);                                              \
  _Pragma("unroll") for (int kx = 0; kx < 2; kx++)                            \
  _Pragma("unroll") for (int i = 0; i < 4; i++)                               \
  _Pragma("unroll") for (int j = 0; j < 2; j++)                               \
      acc[(IO) + i][(JO) + j] = __builtin_amdgcn_mfma_f32_16x16x32_bf16(      \
          AF[i][kx], BF[j][kx], acc[(IO) + i][(JO) + j], 0, 0, 0);            \
  __builtin_amdgcn_s_setprio(0);

#define RD_A(DST, BUF, ROFF)                                                  \
  _Pragma("unroll") for (int i = 0; i < 4; i++)                               \
  _Pragma("unroll") for (int kx = 0; kx < 2; kx++) {                          \
    const int ar = wm * 128 + (ROFF) + i * 16 + fr;                           \
    DST[i][kx] = *(const bf16x8*)&sm[BUF][0][ar]                              \
        [(((kx << 2) + fq8) ^ (ar & 7)) << 3];                                \
  }

#define RD_B(DST, BUF, COFF)                                                  \
  _Pragma("unroll") for (int j = 0; j < 2; j++)                               \
  _Pragma("unroll") for (int kx = 0; kx < 2; kx++) {                          \
    const int br = wn * 64 + (COFF) + j * 16 + fr;                            \
    DST[j][kx] = *(const bf16x8*)&sm[BUF][1][br]                              \
        [(((kx << 2) + fq8) ^ (br & 7)) << 3];                                \
  }

#define PH_SYNC_PRE  __builtin_amdgcn_s_barrier(); __builtin_amdgcn_sched_barrier(0);
#define PH_SYNC_POST __builtin_amdgcn_sched_barrier(0); __builtin_amdgcn_s_barrier();

template <bool RELU, bool OUTF32, int BIASMODE>
__global__ __launch_bounds__(512, 2) void gemm_nt(
    const bf16* __restrict__ A, long sAb, int lda,
    const bf16* __restrict__ B, long sBb, int ldb,
    void* __restrict__ OUT, long sOb,
    const float* __restrict__ bias,
    int M, int N, int Kd) {
  __shared__ bf16 sm[2][2][256][64];   // [buf][0=A,1=B][row][64k] = 128 KiB
  const int t = threadIdx.x;
  const int lane = t & 63;
  const int w = t >> 6;            // 0..7
  const int wm = w >> 2;           // 0..1
  const int wn = w & 3;            // 0..3
  const int n0 = blockIdx.x * 256;
  const int m0 = blockIdx.y * 256;
  const bf16* __restrict__ Ab = A + (size_t)blockIdx.z * sAb;
  const bf16* __restrict__ Bb = B + (size_t)blockIdx.z * sBb;
  const int nk = Kd >> 6;

  const int prow = t >> 3;          // 0..63
  const int pchunk = t & 7;
  const int lch = pchunk ^ (prow & 7);

  const int fr = lane & 15;
  const int fq8 = lane >> 4;        // 0..3

  auto stage = [&](int ab, int h, int kt) {
    const int ktc = (kt < nk) ? kt : 0;   // tail clamp (keeps vmcnt ledger exact)
    const bf16* __restrict__ src = ab ? Bb : Ab;
    const int ld = ab ? ldb : lda;
    const int r0 = (ab ? n0 : m0) + h * 128;
    const int buf = kt & 1;
#pragma unroll
    for (int j = 0; j < 2; j++) {
      const int pr = j * 64 + prow;
      g2lds16(src + (size_t)(r0 + pr) * ld + (ktc << 6) + (lch << 3),
              &sm[buf][ab][h * 128 + pr][pchunk << 3]);
    }
  };

  f32x4 acc[8][4] = {};
  bf16x8 a0[4][2], a1[4][2], b0[2][2], b1[2][2];

  // prologue: tile0 fully + B-halves of tile1; retire tile0 (oldest 8 of 12)
  stage(0, 0, 0); stage(0, 1, 0); stage(1, 0, 0); stage(1, 1, 0);
  stage(1, 0, 1); stage(1, 1, 1);
  asm volatile("s_waitcnt vmcnt(4)" ::: "memory");
  __builtin_amdgcn_s_barrier();
  __builtin_amdgcn_sched_barrier(0);

  for (int T = 0; T < nk; T += 2) {
    // ---- ph1: quadrant (r0,c0) of tile T (buf0)
    RD_A(a0, 0, 0)
    RD_B(b0, 0, 0)
    stage(0, 0, T + 1);
    PH_SYNC_PRE
    MFMA16(a0, b0, 0, 0)
    PH_SYNC_POST
    // ---- ph2
    RD_B(b1, 0, 32)
    stage(0, 1, T + 1);
    PH_SYNC_PRE
    MFMA16(a0, b1, 0, 2)
    PH_SYNC_POST
    // ---- ph3
    RD_A(a1, 0, 64)
    stage(1, 0, T + 2);
    PH_SYNC_PRE
    MFMA16(a1, b0, 4, 0)
    PH_SYNC_POST
    // ---- ph4: ensure tile T+1 landed before ph5 reads
    stage(1, 1, T + 2);
    PH_SYNC_PRE
    MFMA16(a1, b1, 4, 2)
    asm volatile("s_waitcnt vmcnt(4)" ::: "memory");
    PH_SYNC_POST
    // ---- ph5: tile T+1 (buf1)
    RD_A(a0, 1, 0)
    RD_B(b0, 1, 0)
    stage(0, 0, T + 2);
    PH_SYNC_PRE
    MFMA16(a0, b0, 0, 0)
    PH_SYNC_POST
    // ---- ph6
    RD_B(b1, 1, 32)
    stage(0, 1, T + 2);
    PH_SYNC_PRE
    MFMA16(a0, b1, 0, 2)
    PH_SYNC_POST
    // ---- ph7
    RD_A(a1, 1, 64)
    stage(1, 0, T + 3);
    PH_SYNC_PRE
    MFMA16(a1, b0, 4, 0)
    PH_SYNC_POST
    // ---- ph8: ensure tile T+2 landed before next-iter ph1
    stage(1, 1, T + 3);
    PH_SYNC_PRE
    MFMA16(a1, b1, 4, 2)
    asm volatile("s_waitcnt vmcnt(4)" ::: "memory");
    PH_SYNC_POST
  }

  asm volatile("s_waitcnt vmcnt(0)" ::: "memory");

  const int rb = m0 + wm * 128 + (fq8 << 2);
  const int cb = n0 + wn * 64 + fr;
#pragma unroll
  for (int i = 0; i < 8; i++) {
#pragma unroll
    for (int r = 0; r < 4; r++) {
      const int orow = rb + i * 16 + r;
#pragma unroll
      for (int j = 0; j < 4; j++) {
        const int oc = cb + j * 16;
        float vv = acc[i][j][r];
        if (BIASMODE == 1) vv += bias[oc];
        else if (BIASMODE == 2) vv += bias[orow];
        if (RELU) vv = fmaxf(vv, 0.0f);
        if (OUTF32)
          ((float*)OUT)[(size_t)blockIdx.z * sOb + (size_t)orow * N + oc] = vv;
        else
          ((bf16*)OUT)[(size_t)blockIdx.z * sOb + (size_t)orow * N + oc] = (bf16)vv;
      }
    }
  }
}

// ---------------- 128x128 NT GEMM (m97 structure) — for small grids (f_object/f_down) -------
template <bool RELU, bool OUTF32, int BIASMODE>
__global__ __launch_bounds__(256, 2) void gemm_nt128(
    const bf16* __restrict__ A, long sAb, int lda,
    const bf16* __restrict__ B, long sBb, int ldb,
    void* __restrict__ OUT, long sOb,
    const float* __restrict__ bias,
    int M, int N, int Kd) {
  __shared__ bf16 sA[128][64];
  __shared__ bf16 sB[128][64];
  const int n0 = blockIdx.x * 128;
  const int m0 = blockIdx.y * 128;
  const bf16* Ab = A + (size_t)blockIdx.z * sAb;
  const bf16* Bb = B + (size_t)blockIdx.z * sBb;
  const int t = threadIdx.x;
  const int lane = t & 63;
  const int w = t >> 6;
  const int wm = (w & 1) << 6;
  const int wn = (w >> 1) << 6;
  const int srow = t >> 3;
  const int scol = (t & 7) << 3;

  f32x4 acc[4][4] = {};
  const int fr = lane & 15;
  const int fq = (lane >> 4) << 3;

  for (int k0 = 0; k0 < Kd; k0 += 64) {
#pragma unroll
    for (int i = 0; i < 4; i++) {
      g2lds16(Ab + (size_t)(m0 + i * 32 + srow) * lda + (k0 + scol), &sA[i * 32 + srow][scol]);
      g2lds16(Bb + (size_t)(n0 + i * 32 + srow) * ldb + (k0 + scol), &sB[i * 32 + srow][scol]);
    }
    __syncthreads();
#pragma unroll
    for (int kk = 0; kk < 64; kk += 32) {
      bf16x8 af[4], bfv[4];
#pragma unroll
      for (int i = 0; i < 4; i++) af[i] = *(const bf16x8*)&sA[wm + i * 16 + fr][kk + fq];
#pragma unroll
      for (int j = 0; j < 4; j++) bfv[j] = *(const bf16x8*)&sB[wn + j * 16 + fr][kk + fq];
#pragma unroll
      for (int i = 0; i < 4; i++)
#pragma unroll
        for (int j = 0; j < 4; j++)
          acc[i][j] = __builtin_amdgcn_mfma_f32_16x16x32_bf16(af[i], bfv[j], acc[i][j], 0, 0, 0);
    }
    __syncthreads();
  }

  const int rb = m0 + wm + ((lane >> 4) << 2);
  const int cb = n0 + wn + (lane & 15);
#pragma unroll
  for (int i = 0; i < 4; i++) {
#pragma unroll
    for (int r = 0; r < 4; r++) {
      const int orow = rb + i * 16 + r;
#pragma unroll
      for (int j = 0; j < 4; j++) {
        const int oc = cb + j * 16;
        float vv = acc[i][j][r];
        if (BIASMODE == 1) vv += bias[oc];
        else if (BIASMODE == 2) vv += bias[orow];
        if (RELU) vv = fmaxf(vv, 0.0f);
        if (OUTF32)
          ((float*)OUT)[(size_t)blockIdx.z * sOb + (size_t)orow * N + oc] = vv;
        else
          ((bf16*)OUT)[(size_t)blockIdx.z * sOb + (size_t)orow * N + oc] = (bf16)vv;
      }
    }
  }
}

// ---------------- sim + softmax fused, 8-phase: P = softmax_rows(Q.Key^T) ----------------
// Q [z][16384][512], Key [z][256][512] (1/sqrt(C) prefolded), P [z][16384][256] bf16.
// 512 thr / 8 waves; block = 256 q-rows; wave = 32 q-rows x all 256 cols (full row in-reg).
// sm[2][2][256][64] double-buffered, XOR-swizzled; 2 stage-units (64 rows) per phase;
// vmcnt(3) at ph4/ph8 (11 in flight, retire 8 = the tile needed next half-iter).

#define SIM_AQ(BUF)                                                           \
  _Pragma("unroll") for (int i2 = 0; i2 < 2; i2++)                            \
  _Pragma("unroll") for (int kx = 0; kx < 2; kx++) {                          \
    const int ar = wm + i2 * 16 + fr;                                         \
    aq[i2][kx] = *(const bf16x8*)&sm[BUF][0][ar]                              \
        [(((kx << 2) + quad) ^ (ar & 7)) << 3];                               \
  }

#define SIM_BK(BUF, JQ)                                                       \
  _Pragma("unroll") for (int jj = 0; jj < 4; jj++)                            \
  _Pragma("unroll") for (int kx = 0; kx < 2; kx++) {                          \
    const int br = (JQ) * 64 + jj * 16 + fr;                                  \
    bk[jj][kx] = *(const bf16x8*)&sm[BUF][1][br]                              \
        [(((kx << 2) + quad) ^ (br & 7)) << 3];                               \
  }

#define SIM_MM(JQ)                                                            \
  __builtin_amdgcn_s_setprio(1);                                              \
  _Pragma("unroll") for (int kx = 0; kx < 2; kx++)                            \
  _Pragma("unroll") for (int jj = 0; jj < 4; jj++)                            \
  _Pragma("unroll") for (int i2 = 0; i2 < 2; i2++)                            \
    acc[i2][(JQ) * 4 + jj] = __builtin_amdgcn_mfma_f32_16x16x32_bf16(         \
        aq[i2][kx], bk[jj][kx], acc[i2][(JQ) * 4 + jj], 0, 0, 0);             \
  __builtin_amdgcn_s_setprio(0);

__global__ __launch_bounds__(512, 2) void sim_softmax_k(
    const bf16* __restrict__ Q, const bf16* __restrict__ Key, bf16* __restrict__ P) {
  __shared__ bf16 sm[2][2][256][64];   // [buf][0=Q,1=K][row][64] = 128 KiB
  const int t = threadIdx.x;
  const int lane = t & 63;
  const int w = t >> 6;               // 0..7
  const int m0 = blockIdx.x * 256;
  const bf16* Qz = Q + (size_t)blockIdx.y * 16384 * 512;
  const bf16* Kz = Key + (size_t)blockIdx.y * 256 * 512;
  bf16* Pz = P + (size_t)blockIdx.y * 16384 * 256;

  const int fr = lane & 15;
  const int quad = lane >> 4;
  const int wm = w << 5;              // wave's 32 q-rows
  const int prow = t >> 3;            // 0..63 (64 rows per stage unit)
  const int pchunk = t & 7;
  const int lch = pchunk ^ (prow & 7);
  const int nk = 8;

  auto stage = [&](int ab, int u, int kt) {
    const int ktc = (kt < nk) ? kt : 0;
    const bf16* __restrict__ src = ab ? Kz : Qz;
    const int r0 = (ab ? 0 : m0) + u * 64;
    g2lds16(src + (size_t)(r0 + prow) * 512 + (ktc << 6) + (lch << 3),
            &sm[kt & 1][ab][u * 64 + prow][pchunk << 3]);
  };

  f32x4 acc[2][16] = {};
  bf16x8 aq[2][2], bk[4][2];

  // prologue: Q0 u0-3, K0 u0-3, K1 u0-2 = 11 loads; retire tile0's 8
  stage(0, 0, 0); stage(0, 1, 0); stage(0, 2, 0); stage(0, 3, 0);
  stage(1, 0, 0); stage(1, 1, 0); stage(1, 2, 0); stage(1, 3, 0);
  stage(1, 0, 1); stage(1, 1, 1); stage(1, 2, 1);
  asm volatile("s_waitcnt vmcnt(3)" ::: "memory");
  __builtin_amdgcn_s_barrier();
  __builtin_amdgcn_sched_barrier(0);

  for (int T = 0; T < nk; T += 2) {
    // ph1: tile T (buf0), K quarter 0
    SIM_AQ(0)
    SIM_BK(0, 0)
    stage(1, 3, T + 1); stage(0, 0, T + 1);
    PH_SYNC_PRE
    SIM_MM(0)
    PH_SYNC_POST
    // ph2: quarter 1
    SIM_BK(0, 1)
    stage(0, 1, T + 1); stage(0, 2, T + 1);
    PH_SYNC_PRE
    SIM_MM(1)
    PH_SYNC_POST
    // ph3: quarter 2
    SIM_BK(0, 2)
    stage(0, 3, T + 1); stage(1, 0, T + 2);
    PH_SYNC_PRE
    SIM_MM(2)
    PH_SYNC_POST
    // ph4: quarter 3; ensure tile T+1 landed before ph5
    SIM_BK(0, 3)
    stage(1, 1, T + 2); stage(1, 2, T + 2);
    PH_SYNC_PRE
    SIM_MM(3)
    asm volatile("s_waitcnt vmcnt(3)" ::: "memory");
    PH_SYNC_POST
    // ph5: tile T+1 (buf1), quarter 0
    SIM_AQ(1)
    SIM_BK(1, 0)
    stage(1, 3, T + 2); stage(0, 0, T + 2);
    PH_SYNC_PRE
    SIM_MM(0)
    PH_SYNC_POST
    // ph6: quarter 1
    SIM_BK(1, 1)
    stage(0, 1, T + 2); stage(0, 2, T + 2);
    PH_SYNC_PRE
    SIM_MM(1)
    PH_SYNC_POST
    // ph7: quarter 2
    SIM_BK(1, 2)
    stage(0, 3, T + 2); stage(1, 0, T + 3);
    PH_SYNC_PRE
    SIM_MM(2)
    PH_SYNC_POST
    // ph8: quarter 3; ensure tile T+2 landed before next ph1
    SIM_BK(1, 3)
    stage(1, 1, T + 3); stage(1, 2, T + 3);
    PH_SYNC_PRE
    SIM_MM(3)
    asm volatile("s_waitcnt vmcnt(3)" ::: "memory");
    PH_SYNC_POST
  }

  asm volatile("s_waitcnt vmcnt(0)" ::: "memory");

  // epilogue: softmax per row (full row per wave; in-lane over j + shfl over fr group)
#pragma unroll
  for (int i = 0; i < 2; i++) {
#pragma unroll
    for (int r = 0; r < 4; r++) {
      float m = acc[i][0][r];
#pragma unroll
      for (int j = 1; j < 16; j++) m = fmaxf(m, acc[i][j][r]);
#pragma unroll
      for (int o = 1; o < 16; o <<= 1) m = fmaxf(m, __shfl_xor(m, o));
      float sum = 0.0f;
#pragma unroll
      for (int j = 0; j < 16; j++) {
        float e = __expf(acc[i][j][r] - m);
        acc[i][j][r] = e;
        sum += e;
      }
#pragma unroll
      for (int o = 1; o < 16; o <<= 1) sum += __shfl_xor(sum, o);
      float inv = 1.0f / sum;
      const size_t rowoff = (size_t)(m0 + wm + i * 16 + (quad << 2) + r) * 256;
#pragma unroll
      for (int j = 0; j < 16; j++)
        Pz[rowoff + j * 16 + fr] = (bf16)(acc[i][j][r] * inv);
    }
  }
}

extern "C" void kernel_launch(void* const* d_in, const int* in_sizes, int n_in,
                              void* d_out, int out_size, void* d_ws, size_t ws_size,
                              hipStream_t stream) {
  const float* x = (const float*)d_in[0];      // [8, 512, 128, 128]
  const float* proxy = (const float*)d_in[1];  // [8, 512, 256]
  const float* W = (const float*)d_in[2];      // [7, 512, 512]
  const float* s = (const float*)d_in[3];      // [7, 512]
  const float* b = (const float*)d_in[4];      // [7, 512]
  float* out = (float*)d_out;                  // [8, 512, 16384] fp32

  const int C = 512, K = 256, NB = 8, HW = 16384;
  const size_t MiB = 1024 * 1024;
  char* ws = (char*)d_ws;
  if (ws_size < 272 * MiB) return;

  bf16* Wb   = (bf16*)(ws + 0);            // 3.5 MiB
  float* bb  = (float*)(ws + 3670016);
  bf16* W24  = (bf16*)(ws + 4 * MiB);      // [1024][512] = 1 MiB
  float* b24 = (float*)(ws + 5 * MiB);
  bf16* pT   = (bf16*)(ws + 6 * MiB);      // [8][256][512]
  bf16* kt   = (bf16*)(ws + 8 * MiB);      // [8][256][1024]: cols 0-511 k1, 512-1023 t2
  bf16* key  = (bf16*)(ws + 12 * MiB);     // [8][256][512] (1/sqrt(C) folded)
  bf16* v    = (bf16*)(ws + 14 * MiB);     // [8][512][256] value^T
  bf16* bufA = (bf16*)(ws + 16 * MiB);     // 128 MiB: xb -> q -> ctx
  bf16* bufB = (bf16*)(ws + 144 * MiB);    // 128 MiB: t0 -> P

  bf16* xb  = bufA;
  bf16* t0  = bufB;
  bf16* q   = bufA;   // overwrites xb (dead after fp0)
  bf16* P   = bufB;   // overwrites t0 (dead after fp1)
  bf16* ctx = bufA;   // overwrites q  (dead after sim)

  const long KC = (long)K * C;       // 131072
  const long KT = (long)K * 1024;    // 262144
  const long HWC = (long)HW * C;     // 8388608
  const long HWK = (long)HW * K;     // 4194304

  // 1. fold scales into weights (+ build W24 concat)
  prep_weights_k<<<7 * 512 * 512 / 256, 256, 0, stream>>>(W, s, b, Wb, bb, W24, b24);
  // 2. transpose+cast proxy [z,C,K] -> pT [z,K,C]
  transpose_cast_k<<<dim3(K / 64, C / 64, NB), 256, 0, stream>>>(proxy, pT, C, K);
  // 3. transpose+cast x [z,C,HW] -> xb [z,HW,C]
  transpose_cast_k<<<dim3(HW / 64, C / 64, NB), 256, 0, stream>>>(x, xb, C, HW);
  // 4. merged fo0+fd0: kt = relu(pT.W24^T + b24), N=1024  (small grid -> 128^2 kernel)
  gemm_nt128<true, false, 1><<<dim3(1024 / 128, K / 128, NB), 256, 0, stream>>>(
      pT, KC, C, W24, 0, C, kt, KT, b24, K, 1024, C);
  // 5. fo1: key = relu(k1.W3'^T + b3')
  gemm_nt128<true, false, 1><<<dim3(C / 128, K / 128, NB), 256, 0, stream>>>(
      kt, KT, 1024, Wb + 3 * 262144, 0, C, key, KC, bb + 3 * 512, K, C, C);
  // 6. fd1 (swapped): v[c][k] = relu(W5'.t2^T + b5)
  gemm_nt128<true, false, 2><<<dim3(K / 128, C / 128, NB), 256, 0, stream>>>(
      Wb + 5 * 262144, 0, C, kt + 512, KT, 1024, v, KC, bb + 5 * 512, C, K, C);
  // 7. fp0: t0 = relu(xb.W0^T + b0)
  gemm_nt<true, false, 1><<<dim3(C / 256, HW / 256, NB), 512, 0, stream>>>(
      xb, HWC, C, Wb, 0, C, t0, HWC, bb, HW, C, C);
  // 8. fp1: q = relu(t0.W1^T + b1)
  gemm_nt<true, false, 1><<<dim3(C / 256, HW / 256, NB), 512, 0, stream>>>(
      t0, HWC, C, Wb + 1 * 262144, 0, C, q, HWC, bb + 512, HW, C, C);
  // 9. sim + softmax fused (8-phase): P = softmax(q.key^T)
  sim_softmax_k<<<dim3(HW / 256, NB), 512, 0, stream>>>(q, key, P);
  // 10. ctx = P.v^T  [z][HW][512]  (K=256)
  gemm_nt<false, false, 0><<<dim3(C / 256, HW / 256, NB), 512, 0, stream>>>(
      P, HWK, K, v, KC, K, ctx, HWC, nullptr, HW, C, K);
  // 11. fup (swapped): out[c][hw] = relu(W6'.ctx^T + b6), fp32
  gemm_nt<true, true, 2><<<dim3(HW / 256, C / 256, NB), 512, 0, stream>>>(
      Wb + 6 * 262144, 0, C, ctx, HWC, C, out, HWC, bb + 6 * 512, C, HW, C);
}